// Round 10
// baseline (216.955 us; speedup 1.0000x reference)
//
#include <hip/hip_runtime.h>

#define NNODES 100000
#define NBUCK ((NNODES + 127) >> 7)   // 782 buckets of 128 nodes
#define CAPB 3072                     // per-bucket capacity: mean 2046 + 22 sigma
#define BINCAP 16                     // LDS write-combine bin: one 64B line
#define GFILL 512                     // fill blocks: 3 co-resident/CU (LDS-limited)

typedef __attribute__((ext_vector_type(8))) short short8;
typedef __attribute__((ext_vector_type(4))) float f32x4;

// ---- bf16 helpers (storage only; all accumulation fp32) ----
__device__ __forceinline__ float bf2f(unsigned short u) {
    unsigned int v = ((unsigned int)u) << 16;
    return __builtin_bit_cast(float, v);
}
__device__ __forceinline__ unsigned short f2bf(float f) {
    unsigned int u = __builtin_bit_cast(unsigned int, f);
    u += 0x7FFF + ((u >> 16) & 1);   // round-to-nearest-even
    return (unsigned short)(u >> 16);
}

// ============ fill: single-shot LDS binning, one flush ============
// Packed entry: (src << 7) | (dst & 127). gcur = 782 padded cursors (1/64B line).
// GFILL=512 -> 3125 edges/block, mean ~4/bin (BINCAP=16 is ~6-sigma headroom;
// overflow takes the direct-scatter fallback). No windows: 2 barriers total,
// no per-window 782-bin scans. NO per-edge global atomics (round-7: ~30ns each).

__global__ __launch_bounds__(512) void fill_wc(const int* __restrict__ ei, int E,
                                               int* __restrict__ gcur,
                                               int* __restrict__ seg) {
    __shared__ int lcnt[NBUCK];
    __shared__ int lbin[NBUCK * BINCAP];   // 50 KB

    const int t = threadIdx.x;
    for (int i = t; i < NBUCK; i += 512) lcnt[i] = 0;
    __syncthreads();

    const int per = (E + GFILL - 1) / GFILL;
    const int e0 = blockIdx.x * per;
    const int e1 = min(e0 + per, E);

    for (int e = e0 + t; e < e1; e += 512) {
        int src = ei[e];
        int d = ei[E + e];
        int b = (unsigned)d >> 7;
        int p = (src << 7) | (d & 127);
        int pos = atomicAdd(&lcnt[b], 1);
        if (pos < BINCAP) {
            lbin[b * BINCAP + pos] = p;
        } else {
            // rare overflow: direct scatter (correctness fallback)
            int gp = atomicAdd(&gcur[b << 4], 1);
            if (gp < CAPB) seg[b * CAPB + gp] = p;
        }
    }
    __syncthreads();

    // single flush: contiguous c-entry bursts per bucket
    for (int bb = t; bb < NBUCK; bb += 512) {
        int c = min(lcnt[bb], BINCAP);
        if (c > 0) {
            int gp = atomicAdd(&gcur[bb << 4], c);
            int* dp = seg + bb * CAPB;
            const int* sp = lbin + bb * BINCAP;
            for (int j = 0; j < c && gp + j < CAPB; ++j) dp[gp + j] = sp[j];
        }
    }
}

// ============ sortseg: ONE counting sort per bucket, CSR written back IN PLACE ============
// Outputs: seg[bucket] = sorted src ids, rsb/cntb = per-node start/count, dinv.
// 128-wide prefix scan done by wave 0 via shfl (2 elems/lane, 0 internal barriers;
// replaces the 14-barrier LDS Hillis-Steele of rounds 1-9).

__global__ __launch_bounds__(512) void sortseg(const int* __restrict__ gcur,
                                               int* __restrict__ seg,
                                               float* __restrict__ dinv,
                                               int* __restrict__ rsb,
                                               int* __restrict__ cntb, int N) {
    __shared__ int el[CAPB];    // 12 KB
    __shared__ int csr[CAPB];   // 12 KB
    __shared__ int cnt[128], rs[128], cur[128];

    const int t = threadIdx.x, b = blockIdx.x;
    const int total = min(gcur[b << 4], CAPB);

    if (t < 128) cnt[t] = 0;
    __syncthreads();
    {
        const int* sp = seg + b * CAPB;
        for (int i = t; i < total; i += 512) el[i] = sp[i];
    }
    __syncthreads();

    for (int i = t; i < total; i += 512) atomicAdd(&cnt[el[i] & 127], 1);
    __syncthreads();

    // wave-0 exclusive scan of cnt[0..127]
    if (t < 64) {
        int c0 = cnt[2 * t];
        int c1 = cnt[2 * t + 1];
        int s = c0 + c1;
#pragma unroll
        for (int d = 1; d < 64; d <<= 1) {
            int u = __shfl(s, t - d, 64);   // guarded below; OOB lane value unused
            if (t >= d) s += u;
        }
        int ex1 = s - c1;        // exclusive start of node 2t+1
        int ex0 = ex1 - c0;      // exclusive start of node 2t
        rs[2 * t] = ex0;  cur[2 * t] = ex0;
        rs[2 * t + 1] = ex1; cur[2 * t + 1] = ex1;
    }
    __syncthreads();

    for (int i = t; i < total; i += 512) {
        int p = el[i];
        int pos = atomicAdd(&cur[p & 127], 1);
        csr[pos] = (int)((unsigned)p >> 7);
    }
    __syncthreads();

    {
        int* dp = seg + b * CAPB;
        for (int i = t; i < total; i += 512) dp[i] = csr[i];
    }
    if (t < 128) {
        rsb[b * 128 + t] = rs[t];
        cntb[b * 128 + t] = cnt[t];
        int node = (b << 7) + t;
        if (node < N) dinv[node] = rsqrtf((float)cnt[t] + 1.0f);
    }
}

// ========= tiny GEMMs: W12 = W1 @ W2 (128x64), bW2 = b1 @ W2, + MFMA frag pack =========

__global__ __launch_bounds__(256) void w12_kernel(const float* __restrict__ W1,
                                                  const float* __restrict__ b1,
                                                  const float* __restrict__ W2,
                                                  float* __restrict__ W12,
                                                  float* __restrict__ bW2,
                                                  unsigned short* __restrict__ whi,
                                                  unsigned short* __restrict__ wlo) {
    int j = threadIdx.x % 64;
    int r = threadIdx.x / 64;  // 0..3
    if (blockIdx.x < 32) {
        int i = blockIdx.x * 4 + r;       // k index 0..127
        float acc = 0.f;
        for (int k = 0; k < 128; ++k) acc += W1[i * 128 + k] * W2[k * 64 + j];
        W12[i * 64 + j] = acc;
        // fragment emission (B frag: col = lane&15, k = (lane>>4)*8 + jj)
        int kc = i >> 5;
        int ik = i & 31;
        int lane = ((ik >> 3) << 4) | (j & 15);
        int jj = ik & 7;
        int nt = j >> 4;
        size_t idx = (size_t)(((nt << 2) | kc) * 64 + lane) * 8 + jj;
        unsigned short h = f2bf(acc);
        whi[idx] = h;
        wlo[idx] = f2bf(acc - bf2f(h));
    } else if (r == 0) {
        float acc = 0.f;
        for (int k = 0; k < 128; ++k) acc += b1[k] * W2[k * 64 + j];
        bW2[j] = acc;
    }
}

// ========== MFMA GEMM: Ybf[i,:] = bf16( dinv[i] * (X[i,:] @ W12) ), K=128, OD=64 ==========
// Split-bf16: x = xh + xl, w = wh + wl; acc += xh@wh + xh@wl + xl@wh (fp32 MFMA acc).

__global__ __launch_bounds__(256) void gemm_mfma(const float* __restrict__ X,
                                                 const unsigned short* __restrict__ whi,
                                                 const unsigned short* __restrict__ wlo,
                                                 const float* __restrict__ dinv,
                                                 unsigned short* __restrict__ Ybf, int N) {
    const int tid = threadIdx.x;
    const int wv = tid >> 6;
    const int l = tid & 63;
    const int lm = l & 15;
    const int lk = l >> 4;
    const int rowbase = blockIdx.x * 64 + wv * 16;
    const int arow = min(rowbase + lm, N - 1);

    const float* xp = X + (size_t)arow * 128 + lk * 8;

    f32x4 acc[4];
#pragma unroll
    for (int nt = 0; nt < 4; ++nt) acc[nt] = (f32x4){0.f, 0.f, 0.f, 0.f};

#pragma unroll
    for (int kc = 0; kc < 4; ++kc) {
        float4 xa = *(const float4*)(xp + kc * 32);
        float4 xb = *(const float4*)(xp + kc * 32 + 4);
        float xs[8] = {xa.x, xa.y, xa.z, xa.w, xb.x, xb.y, xb.z, xb.w};
        short8 ah, al;
#pragma unroll
        for (int j = 0; j < 8; ++j) {
            unsigned short h = f2bf(xs[j]);
            ah[j] = (short)h;
            al[j] = (short)f2bf(xs[j] - bf2f(h));
        }
#pragma unroll
        for (int nt = 0; nt < 4; ++nt) {
            const size_t fb = (size_t)(((nt << 2) | kc) * 64 + l) * 8;
            short8 bh = *(const short8*)(whi + fb);
            short8 bl = *(const short8*)(wlo + fb);
            acc[nt] = __builtin_amdgcn_mfma_f32_16x16x32_bf16(ah, bh, acc[nt], 0, 0, 0);
            acc[nt] = __builtin_amdgcn_mfma_f32_16x16x32_bf16(ah, bl, acc[nt], 0, 0, 0);
            acc[nt] = __builtin_amdgcn_mfma_f32_16x16x32_bf16(al, bh, acc[nt], 0, 0, 0);
        }
    }

#pragma unroll
    for (int i = 0; i < 4; ++i) {
        int r = rowbase + lk * 4 + i;
        if (r < N) {
            float dv = dinv[r];
#pragma unroll
            for (int nt = 0; nt < 4; ++nt)
                Ybf[(size_t)r * 64 + nt * 16 + lm] = f2bf(acc[nt][i] * dv);
        }
    }
}

// ========== aggregate over presorted CSR: quarter-bucket blocks, 8-lane groups ==========
// 32 groups x 8 lanes, ONE node per group; lane owns 8 cols (16B dwordx4 loads).
// Pure gather, zero atomics.
// FINAL=false: Zbf_i = bf16( dinv_i^2 * (Y_i + sum_src Y_src) )
// FINAL=true : out_i = dinv_i * (Y_i + sum_src Y_src) + s_i*bW2 + b2,
//              s_i = dinv_i*(dinv_i + sum_src dinv_src)

template <bool FINAL>
__global__ __launch_bounds__(256, 8) void agg_csr(const int* __restrict__ seg,
                                                  const int* __restrict__ rsb,
                                                  const int* __restrict__ cntb,
                                                  const unsigned short* __restrict__ Y,
                                                  const float* __restrict__ dinv,
                                                  const float* __restrict__ bW2,
                                                  const float* __restrict__ b2,
                                                  unsigned short* __restrict__ out_bf,
                                                  float* __restrict__ out_f, int N) {
    __shared__ int csrS[CAPB];   // slice of sorted src ids (worst case full bucket)
    __shared__ int rsS[32], cntS[32];

    const int t = threadIdx.x;
    const int b = blockIdx.x >> 2;
    const int q = blockIdx.x & 3;
    const int nb = q << 5;                 // node offset within bucket

    if (t < 32) {
        rsS[t] = rsb[b * 128 + nb + t];
        cntS[t] = cntb[b * 128 + nb + t];
    }
    __syncthreads();
    const int start = rsS[0];
    const int L = rsS[31] + cntS[31] - start;
    {
        const int* sp = seg + (size_t)b * CAPB + start;
        for (int i = t; i < L; i += 256) csrS[i] = sp[i];
    }
    __syncthreads();

    const int g = t >> 3, lane = t & 7, c8 = lane * 8;
    const int node = (b << 7) + nb + g;
    if (node >= N) return;

    float a[8];
    {
        short8 sv = *(const short8*)(Y + (size_t)node * 64 + c8);  // self loop
#pragma unroll
        for (int j = 0; j < 8; ++j) a[j] = bf2f((unsigned short)sv[j]);
    }
    float ds = 0.f;

    const int s0 = rsS[g] - start;
    const int ne = cntS[g];
    const int e0 = s0 + ne;
    int i = s0;

    for (; i + 8 <= e0; i += 8) {
        int a0 = csrS[i + 0];   // LDS broadcast across the 8 lanes
        int a1 = csrS[i + 1];
        int a2 = csrS[i + 2];
        int a3 = csrS[i + 3];
        int a4 = csrS[i + 4];
        int a5 = csrS[i + 5];
        int a6 = csrS[i + 6];
        int a7 = csrS[i + 7];
        short8 v0 = *(const short8*)(Y + (size_t)a0 * 64 + c8);
        short8 v1 = *(const short8*)(Y + (size_t)a1 * 64 + c8);
        short8 v2 = *(const short8*)(Y + (size_t)a2 * 64 + c8);
        short8 v3 = *(const short8*)(Y + (size_t)a3 * 64 + c8);
        short8 v4 = *(const short8*)(Y + (size_t)a4 * 64 + c8);
        short8 v5 = *(const short8*)(Y + (size_t)a5 * 64 + c8);
        short8 v6 = *(const short8*)(Y + (size_t)a6 * 64 + c8);
        short8 v7 = *(const short8*)(Y + (size_t)a7 * 64 + c8);
        if (FINAL) ds += dinv[csrS[i + lane]];   // all 8 lanes used
#pragma unroll
        for (int j = 0; j < 8; ++j) {
            a[j] += bf2f((unsigned short)v0[j]) + bf2f((unsigned short)v1[j])
                  + bf2f((unsigned short)v2[j]) + bf2f((unsigned short)v3[j])
                  + bf2f((unsigned short)v4[j]) + bf2f((unsigned short)v5[j])
                  + bf2f((unsigned short)v6[j]) + bf2f((unsigned short)v7[j]);
        }
    }
    for (; i + 4 <= e0; i += 4) {
        int a0 = csrS[i + 0];
        int a1 = csrS[i + 1];
        int a2 = csrS[i + 2];
        int a3 = csrS[i + 3];
        short8 v0 = *(const short8*)(Y + (size_t)a0 * 64 + c8);
        short8 v1 = *(const short8*)(Y + (size_t)a1 * 64 + c8);
        short8 v2 = *(const short8*)(Y + (size_t)a2 * 64 + c8);
        short8 v3 = *(const short8*)(Y + (size_t)a3 * 64 + c8);
        if (FINAL && lane < 4) ds += dinv[csrS[i + lane]];
#pragma unroll
        for (int j = 0; j < 8; ++j) {
            a[j] += bf2f((unsigned short)v0[j]) + bf2f((unsigned short)v1[j])
                  + bf2f((unsigned short)v2[j]) + bf2f((unsigned short)v3[j]);
        }
    }
    for (; i < e0; ++i) {
        int aa = csrS[i];
        short8 vv = *(const short8*)(Y + (size_t)aa * 64 + c8);
        if (FINAL && lane == 0) ds += dinv[aa];
#pragma unroll
        for (int j = 0; j < 8; ++j) a[j] += bf2f((unsigned short)vv[j]);
    }

    float di = rsqrtf((float)ne + 1.0f);   // == dinv[node]
    if (FINAL) {
        // reduce ds across the 8-lane group (xor 1/2/4 stays within aligned 8-lane sets)
        float dt = ds;
        dt += __shfl_xor(dt, 1, 64);
        dt += __shfl_xor(dt, 2, 64);
        dt += __shfl_xor(dt, 4, 64);
        float si = di * (di + dt);
        float4 bb0 = *(const float4*)(bW2 + c8);
        float4 bb1 = *(const float4*)(bW2 + c8 + 4);
        float4 bv0 = *(const float4*)(b2 + c8);
        float4 bv1 = *(const float4*)(b2 + c8 + 4);
        float4 o0, o1;
        o0.x = di * a[0] + si * bb0.x + bv0.x;
        o0.y = di * a[1] + si * bb0.y + bv0.y;
        o0.z = di * a[2] + si * bb0.z + bv0.z;
        o0.w = di * a[3] + si * bb0.w + bv0.w;
        o1.x = di * a[4] + si * bb1.x + bv1.x;
        o1.y = di * a[5] + si * bb1.y + bv1.y;
        o1.z = di * a[6] + si * bb1.z + bv1.z;
        o1.w = di * a[7] + si * bb1.w + bv1.w;
        *(float4*)(out_f + (size_t)node * 64 + c8) = o0;
        *(float4*)(out_f + (size_t)node * 64 + c8 + 4) = o1;
    } else {
        float d2 = di * di;
        short8 o;
#pragma unroll
        for (int j = 0; j < 8; ++j) o[j] = (short)f2bf(d2 * a[j]);
        *(short8*)(out_bf + (size_t)node * 64 + c8) = o;
    }
}

// ================================ launch ================================

extern "C" void kernel_launch(void* const* d_in, const int* in_sizes, int n_in,
                              void* d_out, int out_size, void* d_ws, size_t ws_size,
                              hipStream_t stream) {
    const float* x  = (const float*)d_in[0];   // [N,128]
    const int*   ei = (const int*)d_in[1];     // [2,E] int32
    const float* W1 = (const float*)d_in[2];   // [128,128]
    const float* b1 = (const float*)d_in[3];   // [128]
    const float* W2 = (const float*)d_in[4];   // [128,64]
    const float* b2 = (const float*)d_in[5];   // [64]
    float* out = (float*)d_out;                // [N,64]

    const int N = NNODES;
    const int E = in_sizes[1] / 2;

    // workspace layout (floats)
    float* ws   = (float*)d_ws;
    float* dinv = ws;                                    // N
    float* W12  = dinv + N;                              // 8192
    float* bW2  = W12 + 8192;                            // 64
    unsigned short* whi = (unsigned short*)(bW2 + 64);   // 8192 ushorts
    unsigned short* wlo = whi + 8192;                    // 8192 ushorts
    unsigned short* ybf = wlo + 8192;                    // N*64 bf16
    unsigned short* zbf = ybf + (size_t)N * 64;          // N*64 bf16
    int*  seg  = (int*)(zbf + (size_t)N * 64);           // NBUCK*CAPB packed ints (9.6 MB)
    int*  gcur = seg + (size_t)NBUCK * CAPB;             // NBUCK*16 padded cursors
    int*  rsb  = gcur + (size_t)NBUCK * 16;              // NBUCK*128
    int*  cntb = rsb + (size_t)NBUCK * 128;              // NBUCK*128

    hipMemsetAsync(gcur, 0, (size_t)NBUCK * 16 * sizeof(int), stream);

    fill_wc<<<GFILL, 512, 0, stream>>>(ei, E, gcur, seg);
    w12_kernel<<<33, 256, 0, stream>>>(W1, b1, W2, W12, bW2, whi, wlo);
    sortseg<<<NBUCK, 512, 0, stream>>>(gcur, seg, dinv, rsb, cntb, N);

    // out = S^2 (X @ W12) + (S 1) (x) (b1@W2) + b2
    gemm_mfma<<<(N + 63) / 64, 256, 0, stream>>>(x, whi, wlo, dinv, ybf, N);
    agg_csr<false><<<NBUCK * 4, 256, 0, stream>>>(seg, rsb, cntb, ybf, dinv, nullptr, nullptr, zbf, nullptr, N);
    agg_csr<true><<<NBUCK * 4, 256, 0, stream>>>(seg, rsb, cntb, zbf, dinv, bW2, b2, nullptr, out, N);
}

// Round 11
// 213.953 us; speedup vs baseline: 1.0140x; 1.0140x over previous
//
#include <hip/hip_runtime.h>

#define NNODES 100000
#define NBUCK ((NNODES + 127) >> 7)   // 782 buckets of 128 nodes
#define CAPB 3072                     // per-bucket capacity: mean 2046 + 22 sigma
#define BINCAP 16                     // LDS write-combine bin: one 64B line
#define GFILL 256                     // fill blocks (round-8 proven form)

typedef __attribute__((ext_vector_type(8))) short short8;
typedef __attribute__((ext_vector_type(4))) float f32x4;

// ---- bf16 helpers (storage only; all accumulation fp32) ----
__device__ __forceinline__ float bf2f(unsigned short u) {
    unsigned int v = ((unsigned int)u) << 16;
    return __builtin_bit_cast(float, v);
}
__device__ __forceinline__ unsigned short f2bf(float f) {
    unsigned int u = __builtin_bit_cast(unsigned int, f);
    u += 0x7FFF + ((u >> 16) & 1);   // round-to-nearest-even
    return (unsigned short)(u >> 16);
}

// ============ fill with LDS write-combining (round-8 proven form) ============
// Packed entry: (src << 7) | (dst & 127). gcur = 782 padded cursors (1/64B line).
// 1024-edge windows; 16-entry (64B) aligned flush bursts. Round-10 lesson: single-shot
// binning at GFILL=512 degrades to mean-4-entry scattered bursts (400K cursor atomics,
// 4x write amplification) -> keep windowed flushes.

__global__ __launch_bounds__(512) void fill_wc(const int* __restrict__ ei, int E,
                                               int* __restrict__ gcur,
                                               int* __restrict__ seg) {
    __shared__ int lcnt[NBUCK];
    __shared__ int lbin[NBUCK * BINCAP];   // 50 KB

    const int t = threadIdx.x;
    for (int i = t; i < NBUCK; i += 512) lcnt[i] = 0;
    __syncthreads();

    const int per = (E + GFILL - 1) / GFILL;
    const int e0 = blockIdx.x * per;
    const int e1 = min(e0 + per, E);

    for (int base = e0; base < e1; base += 1024) {
#pragma unroll
        for (int u = 0; u < 2; ++u) {
            int e = base + u * 512 + t;
            if (e < e1) {
                int src = ei[e];
                int d = ei[E + e];
                int b = (unsigned)d >> 7;
                int p = (src << 7) | (d & 127);
                int pos = atomicAdd(&lcnt[b], 1);
                if (pos < BINCAP) {
                    lbin[b * BINCAP + pos] = p;
                } else {
                    // rare in-window overflow: direct scatter (correctness fallback)
                    int gp = atomicAdd(&gcur[b << 4], 1);
                    if (gp < CAPB) seg[b * CAPB + gp] = p;
                }
            }
        }
        __syncthreads();
        // flush full bins: contiguous 64B of stores per flush
        for (int bb = t; bb < NBUCK; bb += 512) {
            if (lcnt[bb] >= BINCAP) {
                int gp = atomicAdd(&gcur[bb << 4], BINCAP);
                if (gp + BINCAP <= CAPB) {
                    int* dp = seg + bb * CAPB + gp;
                    const int* sp = lbin + bb * BINCAP;
#pragma unroll
                    for (int j = 0; j < BINCAP; ++j) dp[j] = sp[j];
                }
                lcnt[bb] = 0;
            }
        }
        __syncthreads();
    }
    // tail flush (partial lines)
    for (int bb = t; bb < NBUCK; bb += 512) {
        int c = min(lcnt[bb], BINCAP);
        if (c > 0) {
            int gp = atomicAdd(&gcur[bb << 4], c);
            int* dp = seg + bb * CAPB;
            const int* sp = lbin + bb * BINCAP;
            for (int j = 0; j < c && gp + j < CAPB; ++j) dp[gp + j] = sp[j];
        }
    }
}

// ============ stats: per-bucket LDS histogram -> cntb + dinv (no sort, no global atomics) ============

__global__ __launch_bounds__(256) void stats_kernel(const int* __restrict__ gcur,
                                                    const int* __restrict__ seg,
                                                    int* __restrict__ cntb,
                                                    float* __restrict__ dinv, int N) {
    __shared__ int cnt[128];
    const int t = threadIdx.x, b = blockIdx.x;
    if (t < 128) cnt[t] = 0;
    __syncthreads();
    int c = min(gcur[b << 4], CAPB);
    const int* sp = seg + (size_t)b * CAPB;
    for (int i = t; i < c; i += 256) atomicAdd(&cnt[sp[i] & 127], 1);
    __syncthreads();
    if (t < 128) {
        cntb[b * 128 + t] = cnt[t];
        int node = (b << 7) + t;
        if (node < N) dinv[node] = rsqrtf((float)cnt[t] + 1.0f);
    }
}

// ========= tiny GEMMs: W12 = W1 @ W2 (128x64), bW2 = b1 @ W2, + MFMA frag pack =========

__global__ __launch_bounds__(256) void w12_kernel(const float* __restrict__ W1,
                                                  const float* __restrict__ b1,
                                                  const float* __restrict__ W2,
                                                  float* __restrict__ W12,
                                                  float* __restrict__ bW2,
                                                  unsigned short* __restrict__ whi,
                                                  unsigned short* __restrict__ wlo) {
    int j = threadIdx.x % 64;
    int r = threadIdx.x / 64;  // 0..3
    if (blockIdx.x < 32) {
        int i = blockIdx.x * 4 + r;       // k index 0..127
        float acc = 0.f;
        for (int k = 0; k < 128; ++k) acc += W1[i * 128 + k] * W2[k * 64 + j];
        W12[i * 64 + j] = acc;
        // fragment emission (B frag: col = lane&15, k = (lane>>4)*8 + jj)
        int kc = i >> 5;
        int ik = i & 31;
        int lane = ((ik >> 3) << 4) | (j & 15);
        int jj = ik & 7;
        int nt = j >> 4;
        size_t idx = (size_t)(((nt << 2) | kc) * 64 + lane) * 8 + jj;
        unsigned short h = f2bf(acc);
        whi[idx] = h;
        wlo[idx] = f2bf(acc - bf2f(h));
    } else if (r == 0) {
        float acc = 0.f;
        for (int k = 0; k < 128; ++k) acc += b1[k] * W2[k * 64 + j];
        bW2[j] = acc;
    }
}

// ========== MFMA GEMM: Ybf[i,:] = bf16( dinv[i] * (X[i,:] @ W12) ), K=128, OD=64 ==========
// Split-bf16: x = xh + xl, w = wh + wl; acc += xh@wh + xh@wl + xl@wh (fp32 MFMA acc).

__global__ __launch_bounds__(256) void gemm_mfma(const float* __restrict__ X,
                                                 const unsigned short* __restrict__ whi,
                                                 const unsigned short* __restrict__ wlo,
                                                 const float* __restrict__ dinv,
                                                 unsigned short* __restrict__ Ybf, int N) {
    const int tid = threadIdx.x;
    const int wv = tid >> 6;
    const int l = tid & 63;
    const int lm = l & 15;
    const int lk = l >> 4;
    const int rowbase = blockIdx.x * 64 + wv * 16;
    const int arow = min(rowbase + lm, N - 1);

    const float* xp = X + (size_t)arow * 128 + lk * 8;

    f32x4 acc[4];
#pragma unroll
    for (int nt = 0; nt < 4; ++nt) acc[nt] = (f32x4){0.f, 0.f, 0.f, 0.f};

#pragma unroll
    for (int kc = 0; kc < 4; ++kc) {
        float4 xa = *(const float4*)(xp + kc * 32);
        float4 xb = *(const float4*)(xp + kc * 32 + 4);
        float xs[8] = {xa.x, xa.y, xa.z, xa.w, xb.x, xb.y, xb.z, xb.w};
        short8 ah, al;
#pragma unroll
        for (int j = 0; j < 8; ++j) {
            unsigned short h = f2bf(xs[j]);
            ah[j] = (short)h;
            al[j] = (short)f2bf(xs[j] - bf2f(h));
        }
#pragma unroll
        for (int nt = 0; nt < 4; ++nt) {
            const size_t fb = (size_t)(((nt << 2) | kc) * 64 + l) * 8;
            short8 bh = *(const short8*)(whi + fb);
            short8 bl = *(const short8*)(wlo + fb);
            acc[nt] = __builtin_amdgcn_mfma_f32_16x16x32_bf16(ah, bh, acc[nt], 0, 0, 0);
            acc[nt] = __builtin_amdgcn_mfma_f32_16x16x32_bf16(ah, bl, acc[nt], 0, 0, 0);
            acc[nt] = __builtin_amdgcn_mfma_f32_16x16x32_bf16(al, bh, acc[nt], 0, 0, 0);
        }
    }

#pragma unroll
    for (int i = 0; i < 4; ++i) {
        int r = rowbase + lk * 4 + i;
        if (r < N) {
            float dv = dinv[r];
#pragma unroll
            for (int nt = 0; nt < 4; ++nt)
                Ybf[(size_t)r * 64 + nt * 16 + lm] = f2bf(acc[nt][i] * dv);
        }
    }
}

// ========== agg1_fused: full-bucket sort (hidden via co-residency) + gather + dsum ==========
// cnt comes from stats (no re-histogram -> avoids round-8's 4x scan duplication).
// Scatters raw seg -> sorted csr in LDS, writes sorted seg + rsb back for agg2,
// then gathers DIRECTLY from LDS csr (no global->LDS csr staging).
// Also computes dsum[node] = sum_src dinv[src] (graph-only; frees agg2 of dinv gathers).
// Zbf_i = bf16( dinv_i^2 * (Y_i + sum_src Y_src) )

__global__ __launch_bounds__(512) void agg1_fused(const int* __restrict__ gcur,
                                                  int* __restrict__ seg,
                                                  const int* __restrict__ cntb,
                                                  const float* __restrict__ dinv,
                                                  const unsigned short* __restrict__ Y,
                                                  int* __restrict__ rsb,
                                                  float* __restrict__ dsum,
                                                  unsigned short* __restrict__ out_bf, int N) {
    __shared__ int el[CAPB];    // 12 KB raw packed entries
    __shared__ int csr[CAPB];   // 12 KB sorted src ids
    __shared__ int cnt[128], sh[128], rs[128], cur[128];

    const int t = threadIdx.x, b = blockIdx.x;
    const int total = min(gcur[b << 4], CAPB);

    if (t < 128) cnt[t] = cntb[b * 128 + t];
    {
        const int* sp = seg + (size_t)b * CAPB;
        for (int i = t; i < total; i += 512) el[i] = sp[i];
    }
    __syncthreads();

    // exclusive prefix scan of cnt (proven LDS Hillis-Steele)
    int v = (t < 128) ? cnt[t] : 0;
    if (t < 128) sh[t] = v;
    __syncthreads();
    for (int offp = 1; offp < 128; offp <<= 1) {
        int u = (t < 128 && t >= offp) ? sh[t - offp] : 0;
        __syncthreads();
        if (t < 128) sh[t] += u;
        __syncthreads();
    }
    if (t < 128) {
        int excl = sh[t] - v;
        rs[t] = excl;
        cur[t] = excl;
    }
    __syncthreads();

    // scatter into sorted order
    for (int i = t; i < total; i += 512) {
        int p = el[i];
        int pos = atomicAdd(&cur[p & 127], 1);
        csr[pos] = (int)((unsigned)p >> 7);
    }
    __syncthreads();

    // write back sorted seg + rsb for agg2 (hidden under the gather below)
    {
        int* dp = seg + (size_t)b * CAPB;
        for (int i = t; i < total; i += 512) dp[i] = csr[i];
    }
    if (t < 128) rsb[b * 128 + t] = rs[t];

    // gather: 64 groups x 8 lanes, nodes g and g+64
    const int g = t >> 3, lane = t & 7, c8 = lane * 8;
    const int base = b << 7;

#pragma unroll
    for (int k = 0; k < 2; ++k) {
        const int nl = g + (k << 6);
        const int node = base + nl;
        if (node >= N) continue;

        float a[8];
        {
            short8 sv = *(const short8*)(Y + (size_t)node * 64 + c8);  // self loop
#pragma unroll
            for (int j = 0; j < 8; ++j) a[j] = bf2f((unsigned short)sv[j]);
        }
        float ds = 0.f;

        const int s0 = rs[nl];
        const int ne = cnt[nl];
        const int e0 = s0 + ne;
        int i = s0;

        for (; i + 8 <= e0; i += 8) {
            int a0 = csr[i + 0];   // LDS broadcast across the 8 lanes
            int a1 = csr[i + 1];
            int a2 = csr[i + 2];
            int a3 = csr[i + 3];
            int a4 = csr[i + 4];
            int a5 = csr[i + 5];
            int a6 = csr[i + 6];
            int a7 = csr[i + 7];
            short8 v0 = *(const short8*)(Y + (size_t)a0 * 64 + c8);
            short8 v1 = *(const short8*)(Y + (size_t)a1 * 64 + c8);
            short8 v2 = *(const short8*)(Y + (size_t)a2 * 64 + c8);
            short8 v3 = *(const short8*)(Y + (size_t)a3 * 64 + c8);
            short8 v4 = *(const short8*)(Y + (size_t)a4 * 64 + c8);
            short8 v5 = *(const short8*)(Y + (size_t)a5 * 64 + c8);
            short8 v6 = *(const short8*)(Y + (size_t)a6 * 64 + c8);
            short8 v7 = *(const short8*)(Y + (size_t)a7 * 64 + c8);
            ds += dinv[csr[i + lane]];   // 1 load/edge across 8 lanes
#pragma unroll
            for (int j = 0; j < 8; ++j) {
                a[j] += bf2f((unsigned short)v0[j]) + bf2f((unsigned short)v1[j])
                      + bf2f((unsigned short)v2[j]) + bf2f((unsigned short)v3[j])
                      + bf2f((unsigned short)v4[j]) + bf2f((unsigned short)v5[j])
                      + bf2f((unsigned short)v6[j]) + bf2f((unsigned short)v7[j]);
            }
        }
        for (; i + 4 <= e0; i += 4) {
            int a0 = csr[i + 0];
            int a1 = csr[i + 1];
            int a2 = csr[i + 2];
            int a3 = csr[i + 3];
            short8 v0 = *(const short8*)(Y + (size_t)a0 * 64 + c8);
            short8 v1 = *(const short8*)(Y + (size_t)a1 * 64 + c8);
            short8 v2 = *(const short8*)(Y + (size_t)a2 * 64 + c8);
            short8 v3 = *(const short8*)(Y + (size_t)a3 * 64 + c8);
            if (lane < 4) ds += dinv[csr[i + lane]];
#pragma unroll
            for (int j = 0; j < 8; ++j) {
                a[j] += bf2f((unsigned short)v0[j]) + bf2f((unsigned short)v1[j])
                      + bf2f((unsigned short)v2[j]) + bf2f((unsigned short)v3[j]);
            }
        }
        for (; i < e0; ++i) {
            int aa = csr[i];
            short8 vv = *(const short8*)(Y + (size_t)aa * 64 + c8);
            if (lane == 0) ds += dinv[aa];
#pragma unroll
            for (int j = 0; j < 8; ++j) a[j] += bf2f((unsigned short)vv[j]);
        }

        // group-wide dsum (xor 1/2/4 stays within aligned 8-lane sets)
        float dt = ds;
        dt += __shfl_xor(dt, 1, 64);
        dt += __shfl_xor(dt, 2, 64);
        dt += __shfl_xor(dt, 4, 64);
        if (lane == 0) dsum[node] = dt;

        float di = rsqrtf((float)ne + 1.0f);   // == dinv[node]
        float d2 = di * di;
        short8 o;
#pragma unroll
        for (int j = 0; j < 8; ++j) o[j] = (short)f2bf(d2 * a[j]);
        *(short8*)(out_bf + (size_t)node * 64 + c8) = o;
    }
}

// ========== agg2 (final): quarter-bucket pure gather; dsum precomputed by agg1 ==========
// out_i = dinv_i * (Z_i + sum_src Z_src) + s_i*bW2 + b2,  s_i = dinv_i*(dinv_i + dsum_i)

__global__ __launch_bounds__(256, 8) void agg2(const int* __restrict__ seg,
                                               const int* __restrict__ rsb,
                                               const int* __restrict__ cntb,
                                               const unsigned short* __restrict__ Y,
                                               const float* __restrict__ dsum,
                                               const float* __restrict__ bW2,
                                               const float* __restrict__ b2,
                                               float* __restrict__ out_f, int N) {
    __shared__ int csrS[CAPB];   // slice of sorted src ids (worst case full bucket)
    __shared__ int rsS[32], cntS[32];

    const int t = threadIdx.x;
    const int b = blockIdx.x >> 2;
    const int q = blockIdx.x & 3;
    const int nb = q << 5;

    if (t < 32) {
        rsS[t] = rsb[b * 128 + nb + t];
        cntS[t] = cntb[b * 128 + nb + t];
    }
    __syncthreads();
    const int start = rsS[0];
    const int L = rsS[31] + cntS[31] - start;
    {
        const int* sp = seg + (size_t)b * CAPB + start;
        for (int i = t; i < L; i += 256) csrS[i] = sp[i];
    }
    __syncthreads();

    const int g = t >> 3, lane = t & 7, c8 = lane * 8;
    const int node = (b << 7) + nb + g;
    if (node >= N) return;

    float a[8];
    {
        short8 sv = *(const short8*)(Y + (size_t)node * 64 + c8);  // self loop
#pragma unroll
        for (int j = 0; j < 8; ++j) a[j] = bf2f((unsigned short)sv[j]);
    }

    const int s0 = rsS[g] - start;
    const int ne = cntS[g];
    const int e0 = s0 + ne;
    int i = s0;

    for (; i + 8 <= e0; i += 8) {
        int a0 = csrS[i + 0];
        int a1 = csrS[i + 1];
        int a2 = csrS[i + 2];
        int a3 = csrS[i + 3];
        int a4 = csrS[i + 4];
        int a5 = csrS[i + 5];
        int a6 = csrS[i + 6];
        int a7 = csrS[i + 7];
        short8 v0 = *(const short8*)(Y + (size_t)a0 * 64 + c8);
        short8 v1 = *(const short8*)(Y + (size_t)a1 * 64 + c8);
        short8 v2 = *(const short8*)(Y + (size_t)a2 * 64 + c8);
        short8 v3 = *(const short8*)(Y + (size_t)a3 * 64 + c8);
        short8 v4 = *(const short8*)(Y + (size_t)a4 * 64 + c8);
        short8 v5 = *(const short8*)(Y + (size_t)a5 * 64 + c8);
        short8 v6 = *(const short8*)(Y + (size_t)a6 * 64 + c8);
        short8 v7 = *(const short8*)(Y + (size_t)a7 * 64 + c8);
#pragma unroll
        for (int j = 0; j < 8; ++j) {
            a[j] += bf2f((unsigned short)v0[j]) + bf2f((unsigned short)v1[j])
                  + bf2f((unsigned short)v2[j]) + bf2f((unsigned short)v3[j])
                  + bf2f((unsigned short)v4[j]) + bf2f((unsigned short)v5[j])
                  + bf2f((unsigned short)v6[j]) + bf2f((unsigned short)v7[j]);
        }
    }
    for (; i + 4 <= e0; i += 4) {
        int a0 = csrS[i + 0];
        int a1 = csrS[i + 1];
        int a2 = csrS[i + 2];
        int a3 = csrS[i + 3];
        short8 v0 = *(const short8*)(Y + (size_t)a0 * 64 + c8);
        short8 v1 = *(const short8*)(Y + (size_t)a1 * 64 + c8);
        short8 v2 = *(const short8*)(Y + (size_t)a2 * 64 + c8);
        short8 v3 = *(const short8*)(Y + (size_t)a3 * 64 + c8);
#pragma unroll
        for (int j = 0; j < 8; ++j) {
            a[j] += bf2f((unsigned short)v0[j]) + bf2f((unsigned short)v1[j])
                  + bf2f((unsigned short)v2[j]) + bf2f((unsigned short)v3[j]);
        }
    }
    for (; i < e0; ++i) {
        int aa = csrS[i];
        short8 vv = *(const short8*)(Y + (size_t)aa * 64 + c8);
#pragma unroll
        for (int j = 0; j < 8; ++j) a[j] += bf2f((unsigned short)vv[j]);
    }

    float di = rsqrtf((float)ne + 1.0f);
    float si = di * (di + dsum[node]);
    float4 bb0 = *(const float4*)(bW2 + c8);
    float4 bb1 = *(const float4*)(bW2 + c8 + 4);
    float4 bv0 = *(const float4*)(b2 + c8);
    float4 bv1 = *(const float4*)(b2 + c8 + 4);
    float4 o0, o1;
    o0.x = di * a[0] + si * bb0.x + bv0.x;
    o0.y = di * a[1] + si * bb0.y + bv0.y;
    o0.z = di * a[2] + si * bb0.z + bv0.z;
    o0.w = di * a[3] + si * bb0.w + bv0.w;
    o1.x = di * a[4] + si * bb1.x + bv1.x;
    o1.y = di * a[5] + si * bb1.y + bv1.y;
    o1.z = di * a[6] + si * bb1.z + bv1.z;
    o1.w = di * a[7] + si * bb1.w + bv1.w;
    *(float4*)(out_f + (size_t)node * 64 + c8) = o0;
    *(float4*)(out_f + (size_t)node * 64 + c8 + 4) = o1;
}

// ================================ launch ================================

extern "C" void kernel_launch(void* const* d_in, const int* in_sizes, int n_in,
                              void* d_out, int out_size, void* d_ws, size_t ws_size,
                              hipStream_t stream) {
    const float* x  = (const float*)d_in[0];   // [N,128]
    const int*   ei = (const int*)d_in[1];     // [2,E] int32
    const float* W1 = (const float*)d_in[2];   // [128,128]
    const float* b1 = (const float*)d_in[3];   // [128]
    const float* W2 = (const float*)d_in[4];   // [128,64]
    const float* b2 = (const float*)d_in[5];   // [64]
    float* out = (float*)d_out;                // [N,64]

    const int N = NNODES;
    const int E = in_sizes[1] / 2;

    // workspace layout (floats)
    float* ws   = (float*)d_ws;
    float* dinv = ws;                                    // N
    float* dsum = dinv + N;                              // N
    float* W12  = dsum + N;                              // 8192
    float* bW2  = W12 + 8192;                            // 64
    unsigned short* whi = (unsigned short*)(bW2 + 64);   // 8192 ushorts
    unsigned short* wlo = whi + 8192;                    // 8192 ushorts
    unsigned short* ybf = wlo + 8192;                    // N*64 bf16
    unsigned short* zbf = ybf + (size_t)N * 64;          // N*64 bf16
    int*  seg  = (int*)(zbf + (size_t)N * 64);           // NBUCK*CAPB packed ints (9.6 MB)
    int*  gcur = seg + (size_t)NBUCK * CAPB;             // NBUCK*16 padded cursors
    int*  rsb  = gcur + (size_t)NBUCK * 16;              // NBUCK*128
    int*  cntb = rsb + (size_t)NBUCK * 128;              // NBUCK*128

    hipMemsetAsync(gcur, 0, (size_t)NBUCK * 16 * sizeof(int), stream);

    fill_wc<<<GFILL, 512, 0, stream>>>(ei, E, gcur, seg);
    w12_kernel<<<33, 256, 0, stream>>>(W1, b1, W2, W12, bW2, whi, wlo);
    stats_kernel<<<NBUCK, 256, 0, stream>>>(gcur, seg, cntb, dinv, N);

    // out = S^2 (X @ W12) + (S 1) (x) (b1@W2) + b2
    gemm_mfma<<<(N + 63) / 64, 256, 0, stream>>>(x, whi, wlo, dinv, ybf, N);
    agg1_fused<<<NBUCK, 512, 0, stream>>>(gcur, seg, cntb, dinv, ybf, rsb, dsum, zbf, N);
    agg2<<<NBUCK * 4, 256, 0, stream>>>(seg, rsb, cntb, zbf, dsum, bW2, b2, out, N);
}

// Round 12
// 211.370 us; speedup vs baseline: 1.0264x; 1.0122x over previous
//
#include <hip/hip_runtime.h>

#define NNODES 100000
#define NBUCK ((NNODES + 127) >> 7)   // 782 buckets of 128 nodes
#define CAPB 3072                     // per-bucket capacity: mean 2046 + 22 sigma
#define BINCAP 16                     // LDS write-combine bin: one 64B line
#define GFILL 256                     // fill blocks (1 per CU; bounds tail flushes)

typedef __attribute__((ext_vector_type(8))) short short8;
typedef __attribute__((ext_vector_type(4))) float f32x4;

// ---- bf16 helpers (storage only; all accumulation fp32) ----
__device__ __forceinline__ float bf2f(unsigned short u) {
    unsigned int v = ((unsigned int)u) << 16;
    return __builtin_bit_cast(float, v);
}
__device__ __forceinline__ unsigned short f2bf(float f) {
    unsigned int u = __builtin_bit_cast(unsigned int, f);
    u += 0x7FFF + ((u >> 16) & 1);   // round-to-nearest-even
    return (unsigned short)(u >> 16);
}

// ============ fill with LDS write-combining (empirical best: 512-edge windows) ============
// Packed entry: (src << 7) | (dst & 127). gcur = 782 padded cursors (1/64B line).
// NO per-edge global atomics (round-7: ~30ns each, +50us). Windowed 64B flush bursts
// (round-10: single-shot degrades to scattered 4-entry bursts, +5us).

__global__ __launch_bounds__(512) void fill_wc(const int* __restrict__ ei, int E,
                                               int* __restrict__ gcur,
                                               int* __restrict__ seg) {
    __shared__ int lcnt[NBUCK];
    __shared__ int lbin[NBUCK * BINCAP];   // 50 KB

    const int t = threadIdx.x;
    for (int i = t; i < NBUCK; i += 512) lcnt[i] = 0;
    __syncthreads();

    const int per = (E + GFILL - 1) / GFILL;
    const int e0 = blockIdx.x * per;
    const int e1 = min(e0 + per, E);

    for (int base = e0; base < e1; base += 512) {
        int e = base + t;
        if (e < e1) {
            int src = ei[e];
            int d = ei[E + e];
            int b = (unsigned)d >> 7;
            int p = (src << 7) | (d & 127);
            int pos = atomicAdd(&lcnt[b], 1);
            if (pos < BINCAP) {
                lbin[b * BINCAP + pos] = p;
            } else {
                int gp = atomicAdd(&gcur[b << 4], 1);
                if (gp < CAPB) seg[b * CAPB + gp] = p;
            }
        }
        __syncthreads();
        for (int bb = t; bb < NBUCK; bb += 512) {
            if (lcnt[bb] >= BINCAP) {
                int gp = atomicAdd(&gcur[bb << 4], BINCAP);
                if (gp + BINCAP <= CAPB) {
                    int* dp = seg + bb * CAPB + gp;
                    const int* sp = lbin + bb * BINCAP;
#pragma unroll
                    for (int j = 0; j < BINCAP; ++j) dp[j] = sp[j];
                }
                lcnt[bb] = 0;
            }
        }
        __syncthreads();
    }
    for (int bb = t; bb < NBUCK; bb += 512) {
        int c = min(lcnt[bb], BINCAP);
        if (c > 0) {
            int gp = atomicAdd(&gcur[bb << 4], c);
            int* dp = seg + bb * CAPB;
            const int* sp = lbin + bb * BINCAP;
            for (int j = 0; j < c && gp + j < CAPB; ++j) dp[gp + j] = sp[j];
        }
    }
}

// ============ sortseg: ONE counting sort per bucket, CSR written back IN PLACE ============
// (Histogram + sort fused here; separate stats kernel measured neutral-to-worse, R11.)

__global__ __launch_bounds__(512) void sortseg(const int* __restrict__ gcur,
                                               int* __restrict__ seg,
                                               float* __restrict__ dinv,
                                               int* __restrict__ rsb,
                                               int* __restrict__ cntb, int N) {
    __shared__ int el[CAPB];    // 12 KB
    __shared__ int csr[CAPB];   // 12 KB
    __shared__ int cnt[128], sh[128], rs[128], cur[128];

    const int t = threadIdx.x, b = blockIdx.x;
    const int total = min(gcur[b << 4], CAPB);

    if (t < 128) cnt[t] = 0;
    __syncthreads();
    {
        const int* sp = seg + b * CAPB;
        for (int i = t; i < total; i += 512) el[i] = sp[i];
    }
    __syncthreads();

    for (int i = t; i < total; i += 512) atomicAdd(&cnt[el[i] & 127], 1);
    __syncthreads();
    int v = (t < 128) ? cnt[t] : 0;
    if (t < 128) sh[t] = v;
    __syncthreads();
    for (int offp = 1; offp < 128; offp <<= 1) {
        int u = (t < 128 && t >= offp) ? sh[t - offp] : 0;
        __syncthreads();
        if (t < 128) sh[t] += u;
        __syncthreads();
    }
    if (t < 128) {
        int excl = sh[t] - v;
        rs[t] = excl;
        cur[t] = excl;
    }
    __syncthreads();
    for (int i = t; i < total; i += 512) {
        int p = el[i];
        int pos = atomicAdd(&cur[p & 127], 1);
        csr[pos] = (int)((unsigned)p >> 7);
    }
    __syncthreads();

    {
        int* dp = seg + b * CAPB;
        for (int i = t; i < total; i += 512) dp[i] = csr[i];
    }
    if (t < 128) {
        rsb[b * 128 + t] = rs[t];
        cntb[b * 128 + t] = cnt[t];
        int node = (b << 7) + t;
        if (node < N) dinv[node] = rsqrtf((float)cnt[t] + 1.0f);
    }
}

// ========= tiny GEMMs: W12 = W1 @ W2 (128x64), bW2 = b1 @ W2, + MFMA frag pack =========

__global__ __launch_bounds__(256) void w12_kernel(const float* __restrict__ W1,
                                                  const float* __restrict__ b1,
                                                  const float* __restrict__ W2,
                                                  float* __restrict__ W12,
                                                  float* __restrict__ bW2,
                                                  unsigned short* __restrict__ whi,
                                                  unsigned short* __restrict__ wlo) {
    int j = threadIdx.x % 64;
    int r = threadIdx.x / 64;  // 0..3
    if (blockIdx.x < 32) {
        int i = blockIdx.x * 4 + r;       // k index 0..127
        float acc = 0.f;
        for (int k = 0; k < 128; ++k) acc += W1[i * 128 + k] * W2[k * 64 + j];
        W12[i * 64 + j] = acc;
        // fragment emission (B frag: col = lane&15, k = (lane>>4)*8 + jj)
        int kc = i >> 5;
        int ik = i & 31;
        int lane = ((ik >> 3) << 4) | (j & 15);
        int jj = ik & 7;
        int nt = j >> 4;
        size_t idx = (size_t)(((nt << 2) | kc) * 64 + lane) * 8 + jj;
        unsigned short h = f2bf(acc);
        whi[idx] = h;
        wlo[idx] = f2bf(acc - bf2f(h));
    } else if (r == 0) {
        float acc = 0.f;
        for (int k = 0; k < 128; ++k) acc += b1[k] * W2[k * 64 + j];
        bW2[j] = acc;
    }
}

// ========== MFMA GEMM: Ybf[i,:] = bf16( dinv[i] * (X[i,:] @ W12) ), K=128, OD=64 ==========
// Split-bf16: x = xh + xl, w = wh + wl; acc += xh@wh + xh@wl + xl@wh (fp32 MFMA acc).

__global__ __launch_bounds__(256) void gemm_mfma(const float* __restrict__ X,
                                                 const unsigned short* __restrict__ whi,
                                                 const unsigned short* __restrict__ wlo,
                                                 const float* __restrict__ dinv,
                                                 unsigned short* __restrict__ Ybf, int N) {
    const int tid = threadIdx.x;
    const int wv = tid >> 6;
    const int l = tid & 63;
    const int lm = l & 15;
    const int lk = l >> 4;
    const int rowbase = blockIdx.x * 64 + wv * 16;
    const int arow = min(rowbase + lm, N - 1);

    const float* xp = X + (size_t)arow * 128 + lk * 8;

    f32x4 acc[4];
#pragma unroll
    for (int nt = 0; nt < 4; ++nt) acc[nt] = (f32x4){0.f, 0.f, 0.f, 0.f};

#pragma unroll
    for (int kc = 0; kc < 4; ++kc) {
        float4 xa = *(const float4*)(xp + kc * 32);
        float4 xb = *(const float4*)(xp + kc * 32 + 4);
        float xs[8] = {xa.x, xa.y, xa.z, xa.w, xb.x, xb.y, xb.z, xb.w};
        short8 ah, al;
#pragma unroll
        for (int j = 0; j < 8; ++j) {
            unsigned short h = f2bf(xs[j]);
            ah[j] = (short)h;
            al[j] = (short)f2bf(xs[j] - bf2f(h));
        }
#pragma unroll
        for (int nt = 0; nt < 4; ++nt) {
            const size_t fb = (size_t)(((nt << 2) | kc) * 64 + l) * 8;
            short8 bh = *(const short8*)(whi + fb);
            short8 bl = *(const short8*)(wlo + fb);
            acc[nt] = __builtin_amdgcn_mfma_f32_16x16x32_bf16(ah, bh, acc[nt], 0, 0, 0);
            acc[nt] = __builtin_amdgcn_mfma_f32_16x16x32_bf16(ah, bl, acc[nt], 0, 0, 0);
            acc[nt] = __builtin_amdgcn_mfma_f32_16x16x32_bf16(al, bh, acc[nt], 0, 0, 0);
        }
    }

#pragma unroll
    for (int i = 0; i < 4; ++i) {
        int r = rowbase + lk * 4 + i;
        if (r < N) {
            float dv = dinv[r];
#pragma unroll
            for (int nt = 0; nt < 4; ++nt)
                Ybf[(size_t)r * 64 + nt * 16 + lm] = f2bf(acc[nt][i] * dv);
        }
    }
}

// ========== aggregate over presorted CSR: quarter-bucket blocks, 8-lane groups ==========
// 32 groups x 8 lanes, ONE node per group; lane owns 8 cols (16B dwordx4 loads).
// Pure gather, zero atomics. At the LLC random-128B service floor (R3/R5/R11 evidence).
// FINAL=false: Zbf_i = bf16( dinv_i^2 * (Y_i + sum_src Y_src) )
// FINAL=true : out_i = dinv_i * (Y_i + sum_src Y_src) + s_i*bW2 + b2,
//              s_i = dinv_i*(dinv_i + sum_src dinv_src)

template <bool FINAL>
__global__ __launch_bounds__(256, 8) void agg_csr(const int* __restrict__ seg,
                                                  const int* __restrict__ rsb,
                                                  const int* __restrict__ cntb,
                                                  const unsigned short* __restrict__ Y,
                                                  const float* __restrict__ dinv,
                                                  const float* __restrict__ bW2,
                                                  const float* __restrict__ b2,
                                                  unsigned short* __restrict__ out_bf,
                                                  float* __restrict__ out_f, int N) {
    __shared__ int csrS[CAPB];   // slice of sorted src ids (worst case full bucket)
    __shared__ int rsS[32], cntS[32];

    const int t = threadIdx.x;
    const int b = blockIdx.x >> 2;
    const int q = blockIdx.x & 3;
    const int nb = q << 5;                 // node offset within bucket

    if (t < 32) {
        rsS[t] = rsb[b * 128 + nb + t];
        cntS[t] = cntb[b * 128 + nb + t];
    }
    __syncthreads();
    const int start = rsS[0];
    const int L = rsS[31] + cntS[31] - start;
    {
        const int* sp = seg + (size_t)b * CAPB + start;
        for (int i = t; i < L; i += 256) csrS[i] = sp[i];
    }
    __syncthreads();

    const int g = t >> 3, lane = t & 7, c8 = lane * 8;
    const int node = (b << 7) + nb + g;
    if (node >= N) return;

    float a[8];
    {
        short8 sv = *(const short8*)(Y + (size_t)node * 64 + c8);  // self loop
#pragma unroll
        for (int j = 0; j < 8; ++j) a[j] = bf2f((unsigned short)sv[j]);
    }
    float ds = 0.f;

    const int s0 = rsS[g] - start;
    const int ne = cntS[g];
    const int e0 = s0 + ne;
    int i = s0;

    for (; i + 8 <= e0; i += 8) {
        int a0 = csrS[i + 0];   // LDS broadcast across the 8 lanes
        int a1 = csrS[i + 1];
        int a2 = csrS[i + 2];
        int a3 = csrS[i + 3];
        int a4 = csrS[i + 4];
        int a5 = csrS[i + 5];
        int a6 = csrS[i + 6];
        int a7 = csrS[i + 7];
        short8 v0 = *(const short8*)(Y + (size_t)a0 * 64 + c8);
        short8 v1 = *(const short8*)(Y + (size_t)a1 * 64 + c8);
        short8 v2 = *(const short8*)(Y + (size_t)a2 * 64 + c8);
        short8 v3 = *(const short8*)(Y + (size_t)a3 * 64 + c8);
        short8 v4 = *(const short8*)(Y + (size_t)a4 * 64 + c8);
        short8 v5 = *(const short8*)(Y + (size_t)a5 * 64 + c8);
        short8 v6 = *(const short8*)(Y + (size_t)a6 * 64 + c8);
        short8 v7 = *(const short8*)(Y + (size_t)a7 * 64 + c8);
        if (FINAL) ds += dinv[csrS[i + lane]];   // all 8 lanes used
#pragma unroll
        for (int j = 0; j < 8; ++j) {
            a[j] += bf2f((unsigned short)v0[j]) + bf2f((unsigned short)v1[j])
                  + bf2f((unsigned short)v2[j]) + bf2f((unsigned short)v3[j])
                  + bf2f((unsigned short)v4[j]) + bf2f((unsigned short)v5[j])
                  + bf2f((unsigned short)v6[j]) + bf2f((unsigned short)v7[j]);
        }
    }
    for (; i + 4 <= e0; i += 4) {
        int a0 = csrS[i + 0];
        int a1 = csrS[i + 1];
        int a2 = csrS[i + 2];
        int a3 = csrS[i + 3];
        short8 v0 = *(const short8*)(Y + (size_t)a0 * 64 + c8);
        short8 v1 = *(const short8*)(Y + (size_t)a1 * 64 + c8);
        short8 v2 = *(const short8*)(Y + (size_t)a2 * 64 + c8);
        short8 v3 = *(const short8*)(Y + (size_t)a3 * 64 + c8);
        if (FINAL && lane < 4) ds += dinv[csrS[i + lane]];
#pragma unroll
        for (int j = 0; j < 8; ++j) {
            a[j] += bf2f((unsigned short)v0[j]) + bf2f((unsigned short)v1[j])
                  + bf2f((unsigned short)v2[j]) + bf2f((unsigned short)v3[j]);
        }
    }
    for (; i < e0; ++i) {
        int aa = csrS[i];
        short8 vv = *(const short8*)(Y + (size_t)aa * 64 + c8);
        if (FINAL && lane == 0) ds += dinv[aa];
#pragma unroll
        for (int j = 0; j < 8; ++j) a[j] += bf2f((unsigned short)vv[j]);
    }

    float di = rsqrtf((float)ne + 1.0f);   // == dinv[node]
    if (FINAL) {
        // reduce ds across the 8-lane group (xor 1/2/4 stays within aligned 8-lane sets)
        float dt = ds;
        dt += __shfl_xor(dt, 1, 64);
        dt += __shfl_xor(dt, 2, 64);
        dt += __shfl_xor(dt, 4, 64);
        float si = di * (di + dt);
        float4 bb0 = *(const float4*)(bW2 + c8);
        float4 bb1 = *(const float4*)(bW2 + c8 + 4);
        float4 bv0 = *(const float4*)(b2 + c8);
        float4 bv1 = *(const float4*)(b2 + c8 + 4);
        float4 o0, o1;
        o0.x = di * a[0] + si * bb0.x + bv0.x;
        o0.y = di * a[1] + si * bb0.y + bv0.y;
        o0.z = di * a[2] + si * bb0.z + bv0.z;
        o0.w = di * a[3] + si * bb0.w + bv0.w;
        o1.x = di * a[4] + si * bb1.x + bv1.x;
        o1.y = di * a[5] + si * bb1.y + bv1.y;
        o1.z = di * a[6] + si * bb1.z + bv1.z;
        o1.w = di * a[7] + si * bb1.w + bv1.w;
        *(float4*)(out_f + (size_t)node * 64 + c8) = o0;
        *(float4*)(out_f + (size_t)node * 64 + c8 + 4) = o1;
    } else {
        float d2 = di * di;
        short8 o;
#pragma unroll
        for (int j = 0; j < 8; ++j) o[j] = (short)f2bf(d2 * a[j]);
        *(short8*)(out_bf + (size_t)node * 64 + c8) = o;
    }
}

// ================================ launch ================================

extern "C" void kernel_launch(void* const* d_in, const int* in_sizes, int n_in,
                              void* d_out, int out_size, void* d_ws, size_t ws_size,
                              hipStream_t stream) {
    const float* x  = (const float*)d_in[0];   // [N,128]
    const int*   ei = (const int*)d_in[1];     // [2,E] int32
    const float* W1 = (const float*)d_in[2];   // [128,128]
    const float* b1 = (const float*)d_in[3];   // [128]
    const float* W2 = (const float*)d_in[4];   // [128,64]
    const float* b2 = (const float*)d_in[5];   // [64]
    float* out = (float*)d_out;                // [N,64]

    const int N = NNODES;
    const int E = in_sizes[1] / 2;

    // workspace layout (floats)
    float* ws   = (float*)d_ws;
    float* dinv = ws;                                    // N
    float* W12  = dinv + N;                              // 8192
    float* bW2  = W12 + 8192;                            // 64
    unsigned short* whi = (unsigned short*)(bW2 + 64);   // 8192 ushorts
    unsigned short* wlo = whi + 8192;                    // 8192 ushorts
    unsigned short* ybf = wlo + 8192;                    // N*64 bf16
    unsigned short* zbf = ybf + (size_t)N * 64;          // N*64 bf16
    int*  seg  = (int*)(zbf + (size_t)N * 64);           // NBUCK*CAPB packed ints (9.6 MB)
    int*  gcur = seg + (size_t)NBUCK * CAPB;             // NBUCK*16 padded cursors
    int*  rsb  = gcur + (size_t)NBUCK * 16;              // NBUCK*128
    int*  cntb = rsb + (size_t)NBUCK * 128;              // NBUCK*128

    hipMemsetAsync(gcur, 0, (size_t)NBUCK * 16 * sizeof(int), stream);

    fill_wc<<<GFILL, 512, 0, stream>>>(ei, E, gcur, seg);
    w12_kernel<<<33, 256, 0, stream>>>(W1, b1, W2, W12, bW2, whi, wlo);
    sortseg<<<NBUCK, 512, 0, stream>>>(gcur, seg, dinv, rsb, cntb, N);

    // out = S^2 (X @ W12) + (S 1) (x) (b1@W2) + b2
    gemm_mfma<<<(N + 63) / 64, 256, 0, stream>>>(x, whi, wlo, dinv, ybf, N);
    agg_csr<false><<<NBUCK * 4, 256, 0, stream>>>(seg, rsb, cntb, ybf, dinv, nullptr, nullptr, zbf, nullptr, N);
    agg_csr<true><<<NBUCK * 4, 256, 0, stream>>>(seg, rsb, cntb, zbf, dinv, bW2, b2, nullptr, out, N);
}